// Round 11
// baseline (7164.943 us; speedup 1.0000x reference)
//
#include <hip/hip_runtime.h>
#include <hip/hip_bf16.h>

// Problem: B=64, S=512, D=1024, gates N=4096, K=2048 (x ++ h)

typedef __attribute__((ext_vector_type(8))) short bf16x8;
typedef __attribute__((ext_vector_type(16))) float f32x16;
typedef __attribute__((ext_vector_type(4)))  int   i32x4;
typedef __attribute__((ext_vector_type(4)))  float f32x4;

#define AT_RLX __ATOMIC_RELAXED
#define SC_AGT __HIP_MEMORY_SCOPE_AGENT

// ---------- prep kernels ----------

// Wt[n*2048 + k] = bf16(W[k*4096 + n])   (B^T layout: 8 consecutive k per lane)
__global__ __launch_bounds__(256) void conv_w(const float* __restrict__ W,
                                              __hip_bfloat16* __restrict__ Wt) {
    size_t id = (size_t)blockIdx.x * 256 + threadIdx.x;   // < 2048*4096
    int k = (int)(id >> 12);
    int n = (int)(id & 4095);
    Wt[(size_t)n * 2048 + k] = __float2bfloat16(W[id]);
}

// Xt[(s*64+b)*1024 + d] = bf16(X[(b*512+s)*1024 + d])
__global__ __launch_bounds__(256) void conv_x(const float* __restrict__ X,
                                              __hip_bfloat16* __restrict__ Xt) {
    size_t id = (size_t)blockIdx.x * 256 + threadIdx.x;   // < 64*512*1024
    int d   = (int)(id & 1023);
    int row = (int)(id >> 10);
    int s = row >> 6;
    int b = row & 63;
    Xt[id] = __float2bfloat16(X[(((size_t)b * 512 + s) << 10) + d]);
}

// h[b*1024+k] = bf16(hx[k]) broadcast (used only for step 0); zero the epoch flags.
__global__ __launch_bounds__(256) void init_h(const float* __restrict__ hx,
                                              __hip_bfloat16* __restrict__ h,
                                              unsigned int* __restrict__ cflag,
                                              unsigned int* __restrict__ hflag) {
    int id = blockIdx.x * 256 + threadIdx.x;              // < 65536
    h[id] = __float2bfloat16(hx[id & 1023]);
    if (id < 4096) cflag[id] = 0u;                        // 256 flags x 16 u32 pad
    else if (id < 5120) hflag[id - 4096] = 0u;            // 64 flags x 16 u32 pad
}

// ---------- coherence-point primitives ----------
// 16B IF-coherent load (sc0 sc1 dwordx4). Caller must vm_wait0() before consuming.
__device__ __forceinline__ i32x4 ld_cp16(const void* p) {
    i32x4 r;
    asm volatile("global_load_dwordx4 %0, %1, off sc0 sc1"
                 : "=&v"(r) : "v"(p) : "memory");
    return r;
}
__device__ __forceinline__ void vm_wait0() {
    asm volatile("s_waitcnt vmcnt(0)" ::: "memory");
    __builtin_amdgcn_sched_barrier(0);
}
// 8B write EXECUTED AT the IF coherence point: returning agent-scope exchange.
// vmcnt clears only when the old value returns from IF (round-5 lesson).
__device__ __forceinline__ void xchg8f(float* p, float lo, float hi) {
    union { float f[2]; unsigned long long u; } c;
    c.f[0] = lo; c.f[1] = hi;
    unsigned long long old =
        __hip_atomic_exchange((unsigned long long*)p, c.u, AT_RLX, SC_AGT);
    asm volatile("" :: "v"(old));
}
// 8 f32 -> bf16x8 (compiler fuses the scalar converts to v_cvt_pk_bf16_f32)
__device__ __forceinline__ bf16x8 cvt8(const float* p) {
    f32x4 lo = *(const f32x4*)p;
    f32x4 hi = *(const f32x4*)(p + 4);
    bf16x8 r;
#pragma unroll
    for (int e = 0; e < 4; ++e) {
        r[e]     = (short)__builtin_bit_cast(unsigned short, __float2bfloat16(lo[e]));
        r[e + 4] = (short)__builtin_bit_cast(unsigned short, __float2bfloat16(hi[e]));
    }
    return r;
}

// ---------- fused persistent recurrence: flag-pipelined, h rides in `out` ----------
// 256 WGs x 256 thr (1 WG/CU). WG b: nt=b>>1 (col tile), mt=b&1 (row block).
// KEY CHANGE vs r10: h(s) is PUBLISHED AS out[.][s][.] via coherence-point xchg8f
// (values identical to the test's expected output), and CONSUMED with NORMAL CACHED
// loads from out[.][s-1][.]. Each address is written once (at IF) and read once ->
// no stale-line hazard, and the 32 WGs per XCD share the h-panel through their L2:
// IF traffic for the h-broadcast drops 16 MB/step -> ~2 MB/step cold misses.
// comb path, flags, polls: identical to r10 (proven).
__global__ __launch_bounds__(256, 1) void lstm_fused(
    const __hip_bfloat16* __restrict__ Xt,
    const __hip_bfloat16* __restrict__ Wt,
    const __hip_bfloat16* __restrict__ h0buf,
    const float* __restrict__ bias,
    const float* __restrict__ lnw,
    const float* __restrict__ lnb,
    const float* __restrict__ cx,
    float* __restrict__ comb,
    float* __restrict__ out,
    unsigned int* __restrict__ cflag,
    unsigned int* __restrict__ hflag)
{
    const int tid  = threadIdx.x;
    const int lane = tid & 63;
    const int wv   = tid >> 6;          // wave in WG: 0..3
    const int b    = blockIdx.x;        // 0..255

    const int nt = b >> 1;              // col tile 0..127
    const int mt = b & 1;               // row block 0..1
    const int kc = wv;                  // K chunk 0..3  (512 each)
    const int cl = lane & 31;
    const int kh = (lane >> 5) * 8;
    const int n0 = nt * 32;

    __shared__ float lds_f[4096];       // 4 x 32 x 32 split-K partials
    __shared__ float red[8];

    // ---- load this wave's B chunk into registers, once ----
    const short* bp = (const short*)Wt + (size_t)(n0 + cl) * 2048 + kc * 512 + kh;
    bf16x8 breg[32];
#pragma unroll
    for (int i = 0; i < 32; ++i) breg[i] = *(const bf16x8*)(bp + i * 16);

    // ---- A pointers ----
    const short* xbase = (const short*)Xt + (size_t)(mt * 32 + cl) * 1024 + kc * 512 + kh; // + s*65536
    const short* h0row = (const short*)h0buf + (size_t)(mt * 32 + cl) * 1024 + (kc - 2) * 512 + kh;
    const float* hfrow = out + (size_t)(mt * 32 + cl) * 524288 + (kc - 2) * 512 + kh; // + (s-1)*1024
    const unsigned int* myhf = &hflag[(mt * 32 + cl) * 16];   // h-row flag this lane needs
    const unsigned int* mycf = &cflag[(2 * (tid & 127) + (b >> 5)) * 16]; // consumer poll target

    // ---- pointwise persistent state + parameter preloads (rows owned by WGs 0..63) ----
    // thread t owns 4 consecutive outputs o = 4t..4t+3.
    float cr[4];
    f32x4 bias_r[4], lnw_r[4], lnb_r[4];
    if (b < 64) {
#pragma unroll
        for (int e = 0; e < 4; ++e) cr[e] = cx[4 * tid + e];
#pragma unroll
        for (int g = 0; g < 4; ++g) {
            bias_r[g] = *(const f32x4*)&bias[1024 * g + 4 * tid];
            lnw_r[g]  = *(const f32x4*)&lnw[1024 * g + 4 * tid];
            lnb_r[g]  = *(const f32x4*)&lnb[1024 * g + 4 * tid];
        }
    }

    for (int s = 0; s < 512; ++s) {
        // ================= phase 1: GEMM, split-K reduced in LDS =================
        f32x16 accA, accB;
#pragma unroll
        for (int i = 0; i < 16; ++i) { accA[i] = 0.f; accB[i] = 0.f; }
        if (kc < 2) {
            const short* ap = xbase + (size_t)s * 65536;
#pragma unroll
            for (int i = 0; i < 16; ++i) {
                bf16x8 a0 = *(const bf16x8*)(ap + i * 16);
                bf16x8 a1 = *(const bf16x8*)(ap + (i + 16) * 16);
                accA = __builtin_amdgcn_mfma_f32_32x32x16_bf16(a0, breg[i],      accA, 0, 0, 0);
                accB = __builtin_amdgcn_mfma_f32_32x32x16_bf16(a1, breg[i + 16], accB, 0, 0, 0);
            }
        } else {
            // wait for h(s-1): per-lane poll of the one row flag this lane reads
            while (__hip_atomic_load(myhf, AT_RLX, SC_AGT) < (unsigned int)s)
                __builtin_amdgcn_s_sleep(1);
            asm volatile("" ::: "memory");
            if (s == 0) {
                // initial h (bf16, written by init_h; cross-kernel visible)
#pragma unroll
                for (int i = 0; i < 16; ++i) {
                    bf16x8 a0 = *(const bf16x8*)(h0row + i * 16);
                    bf16x8 a1 = *(const bf16x8*)(h0row + (i + 16) * 16);
                    accA = __builtin_amdgcn_mfma_f32_32x32x16_bf16(a0, breg[i],      accA, 0, 0, 0);
                    accB = __builtin_amdgcn_mfma_f32_32x32x16_bf16(a1, breg[i + 16], accB, 0, 0, 0);
                }
            } else {
                // h(s-1) = out[row][s-1][.]: NORMAL cached loads (write-once ring),
                // f32 -> bf16 in-register. L2 shares the panel across the XCD's WGs.
                const float* hf = hfrow + (size_t)(s - 1) * 1024;
#pragma unroll
                for (int i = 0; i < 16; ++i) {
                    bf16x8 a0 = cvt8(hf + i * 16);
                    bf16x8 a1 = cvt8(hf + (i + 16) * 16);
                    accA = __builtin_amdgcn_mfma_f32_32x32x16_bf16(a0, breg[i],      accA, 0, 0, 0);
                    accB = __builtin_amdgcn_mfma_f32_32x32x16_bf16(a1, breg[i + 16], accB, 0, 0, 0);
                }
            }
        }
#pragma unroll
        for (int r = 0; r < 16; ++r) {
            int rl = (r & 3) + 8 * (r >> 2) + 4 * (lane >> 5);
            lds_f[kc * 1024 + rl * 32 + cl] = accA[r] + accB[r];
        }
        __syncthreads();
        {
            float* crow = comb + (size_t)(mt * 32) * 4096 + n0;
#pragma unroll
            for (int half = 0; half < 2; ++half) {
                int e = 2 * tid + half * 512;           // even -> 8B aligned pair
                float2 p0 = *(const float2*)&lds_f[e];
                float2 p1 = *(const float2*)&lds_f[1024 + e];
                float2 p2 = *(const float2*)&lds_f[2048 + e];
                float2 p3 = *(const float2*)&lds_f[3072 + e];
                xchg8f(&crow[(size_t)(e >> 5) * 4096 + (e & 31)],
                       p0.x + p1.x + p2.x + p3.x,
                       p0.y + p1.y + p2.y + p3.y);
            }
        }
        __syncthreads();   // vmcnt(0): exchanges returned from IF -> globally visible
        if (tid == 0)
            __hip_atomic_store(&cflag[b * 16], (unsigned int)(s + 1), AT_RLX, SC_AGT);

        // ================= phase 2: pointwise (rows on WGs 0..63) =================
        if (b < 64) {
            if (tid < 128) {   // one thread per producer WG of this row-block
                while (__hip_atomic_load(mycf, AT_RLX, SC_AGT) < (unsigned int)(s + 1))
                    __builtin_amdgcn_s_sleep(1);
            }
            __syncthreads();
            asm volatile("" ::: "memory");
            const float* c0 = comb + (size_t)b * 4096;
            f32x4 xv[4];
#pragma unroll
            for (int g = 0; g < 4; ++g)
                xv[g] = __builtin_bit_cast(f32x4, ld_cp16(&c0[1024 * g + 4 * tid]));
            vm_wait0();
            float v[4][4];
            float s1 = 0.f, s2 = 0.f;
#pragma unroll
            for (int g = 0; g < 4; ++g)
#pragma unroll
                for (int e = 0; e < 4; ++e) {
                    float x = xv[g][e] + bias_r[g][e];
                    v[g][e] = x;
                    s1 += x;
                    s2 += x * x;
                }
            for (int off = 32; off; off >>= 1) {
                s1 += __shfl_down(s1, off);
                s2 += __shfl_down(s2, off);
            }
            if (lane == 0) { red[2 * wv] = s1; red[2 * wv + 1] = s2; }
            __syncthreads();
            float sum = red[0] + red[2] + red[4] + red[6];
            float ssq = red[1] + red[3] + red[5] + red[7];
            float mean = sum * (1.f / 4096.f);
            float var  = ssq * (1.f / 4096.f) - mean * mean;
            float rstd = rsqrtf(var + 1e-5f);
            float hn[4];
#pragma unroll
            for (int e = 0; e < 4; ++e) {
                float yi = (v[0][e] - mean) * rstd * lnw_r[0][e] + lnb_r[0][e];
                float yf = (v[1][e] - mean) * rstd * lnw_r[1][e] + lnb_r[1][e];
                float yo = (v[2][e] - mean) * rstd * lnw_r[2][e] + lnb_r[2][e];
                float yh = (v[3][e] - mean) * rstd * lnw_r[3][e] + lnb_r[3][e];
                float ig = 1.f / (1.f + __expf(-yi));
                float fg = 1.f / (1.f + __expf(-yf));
                float og = 1.f / (1.f + __expf(-yo));
                float hd = tanhf(yh);
                float cn = fg * cr[e] + ig * hd;
                cr[e] = cn;
                hn[e] = og * tanhf(cn);
            }
            // publish h(s) AS out(s) at the coherence point (2 x 8B returning xchg),
            // then drain + flag. This is both the test output and next step's h.
            float* orow = out + (size_t)b * 524288 + (size_t)s * 1024 + 4 * tid;
            xchg8f(orow,     hn[0], hn[1]);
            xchg8f(orow + 2, hn[2], hn[3]);
            __syncthreads();   // vmcnt(0): out(s) at coherence point
            if (tid == 0)
                __hip_atomic_store(&hflag[b * 16], (unsigned int)(s + 1), AT_RLX, SC_AGT);
        }
    }
}

// ---------- launcher ----------
extern "C" void kernel_launch(void* const* d_in, const int* in_sizes, int n_in,
                              void* d_out, int out_size, void* d_ws, size_t ws_size,
                              hipStream_t stream) {
    const float* X   = (const float*)d_in[0];   // [64,512,1024]
    const float* W   = (const float*)d_in[1];   // [2048,4096]
    const float* bv  = (const float*)d_in[2];   // [4096]
    const float* lnw = (const float*)d_in[3];   // [4096]
    const float* lnb = (const float*)d_in[4];   // [4096]
    const float* hx  = (const float*)d_in[5];   // [1,1024]
    const float* cx  = (const float*)d_in[6];   // [1,1024]
    float* out = (float*)d_out;                 // [64,512,1024]

    char* base = (char*)d_ws;
    __hip_bfloat16* Wt    = (__hip_bfloat16*)(base);                 // 16 MB
    __hip_bfloat16* Xt    = (__hip_bfloat16*)(base + 16777216);      // 64 MB
    float*          comb  = (float*)         (base + 83886080);      // 1 MB
    __hip_bfloat16* hbuf  = (__hip_bfloat16*)(base + 84934656);      // 128 KB
    unsigned int*   cflag = (unsigned int*)  (base + 85065728);      // 16 KB (256 x 64B)
    unsigned int*   hflag = (unsigned int*)  (base + 85082112);      // 4 KB  (64 x 64B)
    // total ~85.09 MB

    conv_w<<<32768, 256, 0, stream>>>(W, Wt);
    conv_x<<<131072, 256, 0, stream>>>(X, Xt);
    init_h<<<256, 256, 0, stream>>>(hx, hbuf, cflag, hflag);

    lstm_fused<<<256, 256, 0, stream>>>(Xt, Wt, hbuf, bv, lnw, lnb, cx, comb, out,
                                        cflag, hflag);
}